// Round 6
// baseline (565.900 us; speedup 1.0000x reference)
//
#include <hip/hip_runtime.h>
#include <cstdint>
#include <cstddef>

// ---------------- problem constants ----------------
#define BATCH  16
#define DIMK   512
#define LEN    4096        // frames T == L
#define NFFT   1024
#define HOPS   256
#define PADT   384         // (WIN-HOP)/2
#define OUTL   1048576     // per-batch output length = L*HOP
#define KP2    1056        // S row: 528 complex bins interleaved (513 used + pad)
#define KP2U   528         // uint32 words per S row
#define K2     4224        // D' row length = 4*1056 (r-segments)

typedef __attribute__((ext_vector_type(8))) short  short8;
typedef __attribute__((ext_vector_type(4))) float  f32x4;

__device__ __forceinline__ unsigned short f2bf(float f) {
    unsigned u = __float_as_uint(f);
    u += 0x7FFFu + ((u >> 16) & 1u);     // RNE
    return (unsigned short)(u >> 16);
}

__device__ __forceinline__ int clampL(int v) {
    return v < 0 ? 0 : (v > LEN - 1 ? LEN - 1 : v);
}

// async global->LDS, 16B per lane; LDS dest is wave-uniform base + lane*16.
__device__ __forceinline__ void gld16(const unsigned short* g, unsigned short* l) {
    __builtin_amdgcn_global_load_lds(
        (const __attribute__((address_space(1))) unsigned int*)(const void*)g,
        (__attribute__((address_space(3))) unsigned int*)(void*)l, 16, 0, 0);
}

// ---------------- pack W (gather mag/phase rows pairwise into M-tiles) -------
__global__ void pack_W(const float* __restrict__ W, const float* __restrict__ bvec,
                       unsigned short* __restrict__ Wb, float* __restrict__ bp) {
    const int r = blockIdx.x;               // 0..1151
    const int i = r >> 7, j = r & 127;
    const int src = (j < 64) ? (i * 64 + j) : (1024 + i * 64 + (j - 64));
    for (int c = threadIdx.x; c < DIMK; c += 256)
        Wb[r * DIMK + c] = f2bf(W[src * DIMK + c]);
    if (threadIdx.x == 0) bp[r] = bvec[src];
}

// ---------------- transpose x (B,512,L) f32 -> xT (B,L,512) bf16 -------------
__global__ void transpose_x(const float* __restrict__ x, unsigned short* __restrict__ xT) {
    __shared__ float tile[32][33];
    const int b = blockIdx.z;
    const int l0 = blockIdx.x * 32, d0 = blockIdx.y * 32;
    const int tx = threadIdx.x, ty = threadIdx.y;        // 32 x 8
#pragma unroll
    for (int i = 0; i < 4; ++i)
        tile[ty + 8 * i][tx] = x[((size_t)b * DIMK + d0 + ty + 8 * i) * LEN + l0 + tx];
    __syncthreads();
#pragma unroll
    for (int i = 0; i < 4; ++i)
        xT[((size_t)b * LEN + l0 + ty + 8 * i) * DIMK + d0 + tx] = f2bf(tile[tx][ty + 8 * i]);
}

// ---------------- build D' : 256 x 4224 bf16 ---------------------------------
__global__ void build_D(unsigned short* __restrict__ D) {
    const int idx = blockIdx.x * 256 + threadIdx.x;
    if (idx >= 256 * K2) return;
    const int srow = idx / K2;
    const int col  = idx - srow * K2;
    const int rseg = col / KP2;
    const int jj   = col - rseg * KP2;
    const int n    = srow + 256 * rseg;
    const int k    = jj >> 1;
    const float wv = 0.5f - 0.5f * __cosf((float)n * (6.283185307179586f / 1024.f));
    float v = 0.f;
    if ((jj & 1) == 0) {                                  // Re coefficient
        if (k == 0)        v = wv * (1.f / 1024.f);
        else if (k < 512) {
            const int p = (k * n) & 1023;
            v = 2.f * __cosf((float)p * (6.283185307179586f / 1024.f)) * wv * (1.f / 1024.f);
        } else if (k == 512) v = ((n & 1) ? -wv : wv) * (1.f / 1024.f);
    } else {                                              // Im coefficient
        if (k >= 1 && k < 512) {
            const int p = (k * n) & 1023;
            v = -2.f * __sinf((float)p * (6.283185307179586f / 1024.f)) * wv * (1.f / 1024.f);
        }
    }
    D[idx] = f2bf(v);
}

// ---------------- GEMM1: h = Wb @ xT^T, fused exp/clip/sincos -> S -----------
// (verified baseline; untouched for attribution)
__global__ __launch_bounds__(256)
void gemm1_kernel(const unsigned short* __restrict__ A,
                  const unsigned short* __restrict__ Bm,
                  const float* __restrict__ bp,
                  unsigned* __restrict__ Sout)
{
    __shared__ alignas(16) char smem[17408];
    unsigned short* Alds = (unsigned short*)smem;            // 8192 B
    unsigned short* Blds = (unsigned short*)(smem + 8192);   // 8192 B
    unsigned*       epi  = (unsigned*)smem;                  // 64 x 68 u32 = 17408 B

    const int tid  = threadIdx.x;
    const int lane = tid & 63, w = tid >> 6;
    const int quad = lane >> 4, ln = lane & 15;
    const int bx = blockIdx.x, by = blockIdx.y, bz = blockIdx.z;
    const int l0 = bx * 128;

    const int c0 = tid, c1 = tid + 256;    // chunk -> row c>>2, colchunk c&3
    const unsigned short* Bsrc0 = Bm + ((size_t)bz * LEN + l0 + (c0 >> 2)) * DIMK + (c0 & 3) * 8;
    const unsigned short* Bsrc1 = Bm + ((size_t)bz * LEN + l0 + (c1 >> 2)) * DIMK + (c1 & 3) * 8;

    for (int mi = 0; mi < 3; ++mi) {
        const int mt = by * 3 + mi;
        const int m0 = mt * 128;
        const int kbase = mt * 64;

        const unsigned short* Asrc0 = A + (size_t)(m0 + (c0 >> 2)) * DIMK + (c0 & 3) * 8;
        const unsigned short* Asrc1 = A + (size_t)(m0 + (c1 >> 2)) * DIMK + (c1 & 3) * 8;

        f32x4 acc[8][2];
#pragma unroll
        for (int a = 0; a < 8; ++a)
#pragma unroll
            for (int c = 0; c < 2; ++c) acc[a][c] = (f32x4){0.f, 0.f, 0.f, 0.f};

        for (int k0 = 0; k0 < DIMK; k0 += 32) {
            gld16(Asrc0 + k0, &Alds[c0 * 8]);
            gld16(Asrc1 + k0, &Alds[c1 * 8]);
            gld16(Bsrc0 + k0, &Blds[c0 * 8]);
            gld16(Bsrc1 + k0, &Blds[c1 * 8]);
            __syncthreads();

            short8 af[8], bfr[2];
#pragma unroll
            for (int rt = 0; rt < 8; ++rt)
                af[rt] = *(const short8*)&Alds[((16 * rt + ln) * 4 + quad) * 8];
#pragma unroll
            for (int ct = 0; ct < 2; ++ct)
                bfr[ct] = *(const short8*)&Blds[((32 * w + 16 * ct + ln) * 4 + quad) * 8];
#pragma unroll
            for (int rt = 0; rt < 8; ++rt)
#pragma unroll
                for (int ct = 0; ct < 2; ++ct)
                    acc[rt][ct] = __builtin_amdgcn_mfma_f32_16x16x32_bf16(af[rt], bfr[ct], acc[rt][ct], 0, 0, 0);
            __syncthreads();
        }

        // epilogue: 2 passes over ct; LDS rows = w*16+ln (64 l-rows), cols = k
#pragma unroll
        for (int ct = 0; ct < 2; ++ct) {
            const int lrow = w * 16 + ln;
#pragma unroll
            for (int rt = 0; rt < 4; ++rt) {
                unsigned pk[4];
#pragma unroll
                for (int reg = 0; reg < 4; ++reg) {
                    const int rloc = 16 * rt + quad * 4 + reg;
                    const float hm = acc[rt][ct][reg]     + bp[m0 + rloc];
                    const float hp = acc[rt + 4][ct][reg] + bp[m0 + 64 + rloc];
                    const float mag = fminf(__expf(hm), 100.0f);
                    pk[reg] = (unsigned)f2bf(mag * __cosf(hp)) |
                              ((unsigned)f2bf(mag * __sinf(hp)) << 16);
                }
                *(uint4*)&epi[lrow * 68 + 16 * rt + 4 * quad] = *(uint4*)pk;
            }
            __syncthreads();
            // reader: 1024 16B-chunks; chunk c -> lrow c>>4, kchunk c&15
#pragma unroll
            for (int i = 0; i < 4; ++i) {
                const int c = i * 256 + tid;
                const int row = c >> 4, kc = c & 15;
                if (kbase + kc * 4 < KP2U) {
                    const int l = l0 + 32 * (row >> 4) + 16 * ct + (row & 15);
                    uint4 v = *(const uint4*)&epi[row * 68 + kc * 4];
                    *(uint4*)&Sout[((size_t)bz * LEN + l) * KP2U + kbase + kc * 4] = v;
                }
            }
            __syncthreads();
        }
    }
}

// ---------------- OLA envelope (edges only; interior = 1.5 by COLA) ----------
__device__ __forceinline__ float env_at(int q, int s) {
    float env = 0.f;
#pragma unroll
    for (int r = 0; r < 4; ++r) {
        const int t = q - r;
        if (t >= 0 && t < LEN) {
            const float w = 0.5f - 0.5f * __cosf((float)(s + 256 * r) * (6.283185307179586f / 1024.f));
            env += w * w;
        }
    }
    return env;
}

// ---------------- GEMM2 v5b: per-wave A pipeline, 1 barrier per kk -----------
// Design rule after v2-v4 failures: NO wave ever reads LDS written by another
// wave's global_load_lds under a counted (non-zero) vmcnt. Each wave stages
// its OWN 64-row A-chunk (4 gld16/rseg) into a PRIVATE 2-buffer ring; ordering
// is same-wave vmcnt only (verified m97/m131 semantics).
// Per-wave FIFO ledger per kk (region-fenced with sched_barrier(0)):
//   entry: [A(kk,0)x4, A(kk,1)x4] + loadB(kk+1) regs [+3]      = 11
//   r0: vmcnt(7) -> A(kk,0) done; MFMA buf0; lgkm0; stage A(kk,2)->buf0  [11]
//   r1: vmcnt(7) -> A(kk,1) done; MFMA buf1; lgkm0; stage A(kk,3)->buf1  [11]
//   r2: vmcnt(4) -> B+A(kk,2) done; [B keep-alive here: wait is a no-op];
//       MFMA buf0; lgkm0; stage A(kk+1,0)                                [8]
//   r3: vmcnt(4) -> A(kk,3) done; MFMA buf1; lgkm0; stage A(kk+1,1)      [8]
//   kk-end: ds_write B half^1 (regs long since complete); lgkm0; s_barrier
// v5b fix: keep-alive asm on B regs at r2 (rule #17) prevents last-iteration
// peel+DCE of loadB (which would shift the vmcnt FIFO by 3 and break r0/r1).
// Placed at r2 because B is ledger-complete there -> forced wait is a no-op.
__global__ __launch_bounds__(256)
void gemm2_kernel(const unsigned short* __restrict__ D,   // 256 x 4224
                  const unsigned short* __restrict__ Sm,  // (bz*LEN + l)*1056 bf16
                  float* __restrict__ yout)
{
    __shared__ alignas(16) char smem[49664];
    // per-wave A: wave w at [w*8192, w*8192+8192): 2 bufs x 4096 B
    // B ping-pong: [32768, 49664): 2 halves x 8448 B
    unsigned short* Bh  = (unsigned short*)(smem + 32768);
    float*          epi = (float*)smem;                   // 16896 B, aliases A region

    const int tid  = threadIdx.x;
    const int lane = tid & 63, w = tid >> 6;
    const int quad = lane >> 4, ln = lane & 15;
    const int sh = w >> 1, qh = w & 1;
    const int bx = blockIdx.x, by = blockIdx.y, bz = blockIdx.z;
    const int qt0 = bx * 128, s0 = by * 128;

    unsigned short* AW = (unsigned short*)smem + w * 4096;   // 4096 shorts per wave

    const size_t srowbase = (size_t)bz * LEN;
    const int ca0 = tid, ca1 = tid + 256;   // B chunks: row c>>2, kchunk c&3
    const int c2  = 512 + (tid & 15);       // tail chunk: uniform LOAD for all lanes
    const int c2w = 512 + tid;              // tail chunk: WRITE only for tid<16

    // B source addresses (clamped; loads unconditional so vm count is uniform)
    const int le0 = qt0 + (ca0 >> 2) - 2;
    const int le1 = qt0 + (ca1 >> 2) - 2;
    const int le2 = qt0 + (c2  >> 2) - 2;
    const size_t ba0 = (srowbase + (size_t)clampL(le0)) * KP2 + (ca0 & 3) * 8;
    const size_t ba1 = (srowbase + (size_t)clampL(le1)) * KP2 + (ca1 & 3) * 8;
    const size_t ba2 = (srowbase + (size_t)clampL(le2)) * KP2 + (c2  & 3) * 8;
    const bool ok0 = (unsigned)le0 < (unsigned)LEN;
    const bool ok1 = (unsigned)le1 < (unsigned)LEN;
    const bool ok2 = (unsigned)le2 < (unsigned)LEN;
    const uint4 zz = {0u, 0u, 0u, 0u};

    // per-lane A source base: lane covers row s0+64*sh+(lane>>2), kchunk lane&3
    const unsigned short* Dw = D + (size_t)(s0 + 64 * sh + (lane >> 2)) * K2 + (lane & 3) * 8;
    unsigned short* ALn = AW + lane * 8;

    // stage this wave's 64x32 A-subtile for (kkel, rseg) into private buf.
    // LDS offset algebra: row rl=(lane>>2)+16j lands at rl*32+(lane&3)*8 ->
    // linear row-major [64][32] per buf.
    auto stageA = [&](int kkel, int rseg, int buf) {
        const unsigned short* p = Dw + rseg * KP2 + kkel;
        unsigned short* l = ALn + buf * 2048;
#pragma unroll
        for (int j = 0; j < 4; ++j)                       // rows 16j..16j+15
            gld16(p + (size_t)(16 * j) * K2, l + j * 512);
    };

    f32x4 acc[4][4];
#pragma unroll
    for (int a = 0; a < 4; ++a)
#pragma unroll
        for (int c = 0; c < 4; ++c) acc[a][c] = (f32x4){0.f, 0.f, 0.f, 0.f};

    auto mfmaStep = [&](int rr, int buf, int h) {
        short8 af[4], bfr[4];
#pragma unroll
        for (int rt = 0; rt < 4; ++rt)
            af[rt] = *(const short8*)&AW[buf * 2048 + (16 * rt + ln) * 32 + quad * 8];
#pragma unroll
        for (int ct = 0; ct < 4; ++ct)
            bfr[ct] = *(const short8*)&Bh[h * 4224 + ((3 - rr + 64 * qh + 16 * ct + ln) * 4 + quad) * 8];
#pragma unroll
        for (int rt = 0; rt < 4; ++rt)
#pragma unroll
            for (int ct = 0; ct < 4; ++ct)
                acc[rt][ct] = __builtin_amdgcn_mfma_f32_16x16x32_bf16(af[rt], bfr[ct], acc[rt][ct], 0, 0, 0);
    };

    uint4 v0, v1, v2;
    auto loadB = [&](int kkel) {
        v0 = *(const uint4*)&Sm[ba0 + kkel];
        v1 = *(const uint4*)&Sm[ba1 + kkel];
        v2 = *(const uint4*)&Sm[ba2 + kkel];
        if (!ok0) v0 = zz;
        if (!ok1) v1 = zz;
        if (!ok2) v2 = zz;
    };
    auto writeB = [&](int h) {
        unsigned short* Bp = Bh + h * 4224;
        *(uint4*)&Bp[ca0 * 8] = v0;
        *(uint4*)&Bp[ca1 * 8] = v1;
        if (tid < 16) *(uint4*)&Bp[c2w * 8] = v2;
    };

#define WAITVM(NSTR)                                                        \
    asm volatile("s_waitcnt vmcnt(" NSTR ")" ::: "memory");                 \
    __builtin_amdgcn_sched_barrier(0);
#define LGKM0                                                               \
    asm volatile("s_waitcnt lgkmcnt(0)" ::: "memory");                      \
    __builtin_amdgcn_sched_barrier(0);

    // ---- prologue: B(0) regs first, own A(0,{0,1}) into bufs, publish B(0) --
    loadB(0);
    stageA(0, 0, 0);
    stageA(0, 1, 1);
    writeB(0);                      // compiler inserts exact vmcnt for B regs
    LGKM0
    __builtin_amdgcn_s_barrier();
    __builtin_amdgcn_sched_barrier(0);

    for (int kkIdx = 0; kkIdx < 33; ++kkIdx) {
        const int kk  = kkIdx * 32;
        const int kkn = (kkIdx < 32) ? kk + 32 : kk;      // clamped tail (dummy)
        const int h   = kkIdx & 1;

        loadB(kkn);                                       // +3 (spans all rsegs)
        // r0
        WAITVM("7")
        mfmaStep(0, 0, h);
        LGKM0
        stageA(kk, 2, 0);
        // r1
        WAITVM("7")
        mfmaStep(1, 1, h);
        LGKM0
        stageA(kk, 3, 1);
        // r2
        WAITVM("4")
        // B(kkn) is ledger-complete here -> this keep-alive's implicit wait is
        // a no-op; it pins the loadB instructions against last-iteration DCE.
        asm volatile("" :: "v"(v0.x), "v"(v0.y), "v"(v0.z), "v"(v0.w),
                           "v"(v1.x), "v"(v1.y), "v"(v1.z), "v"(v1.w),
                           "v"(v2.x), "v"(v2.y), "v"(v2.z), "v"(v2.w));
        mfmaStep(2, 0, h);
        LGKM0
        stageA(kkn, 0, 0);
        // r3
        WAITVM("4")
        mfmaStep(3, 1, h);
        LGKM0
        stageA(kkn, 1, 1);
        // kk end: publish B(kk+1) into the other half; ONE barrier per kk
        if (kkIdx != 32) {
            writeB(h ^ 1);          // compiler's own vmcnt covers the B regs
            LGKM0
            __builtin_amdgcn_s_barrier();
            __builtin_amdgcn_sched_barrier(0);
        }
    }
#undef WAITVM
#undef LGKM0

    // drain dummy tail DMAs + everything before smem is reused as epilogue buf
    asm volatile("s_waitcnt vmcnt(0) lgkmcnt(0)" ::: "memory");
    __syncthreads();

    // ---- epilogue: 4 passes over ct; LDS rows = qh*16+ln (32 qi), cols = s ----
    float* yb = yout + (size_t)bz * OUTL;
#pragma unroll
    for (int ct = 0; ct < 4; ++ct) {
        const int qrow = qh * 16 + ln;
#pragma unroll
        for (int rt = 0; rt < 4; ++rt)
            *(f32x4*)&epi[qrow * 132 + 64 * sh + 16 * rt + 4 * quad] = acc[rt][ct];
        __syncthreads();
        // reader: 1024 16B-chunks; chunk c -> qrow c>>5, s-chunk c&31
#pragma unroll
        for (int i = 0; i < 4; ++i) {
            const int c = i * 256 + tid;
            const int row = c >> 5, sc = c & 31;
            const int qi = qt0 + 64 * (row >> 4) + 16 * ct + (row & 15);
            const int q = qi + 1;
            const int j = 256 * qi + (s0 + sc * 4) - 128;
            if ((unsigned)j < (unsigned)(OUTL - 3)) {
                f32x4 v = *(const f32x4*)&epi[row * 132 + sc * 4];
                if (q >= 3 && q <= 4095) {
                    v *= (2.0f / 3.0f);
                } else {
#pragma unroll
                    for (int e = 0; e < 4; ++e)
                        v[e] /= env_at(q, s0 + sc * 4 + e);
                }
                *(f32x4*)&yb[j] = v;
            }
        }
        __syncthreads();
    }
}

// ---------------- launch -----------------------------------------------------
// Workspace layout (~209 MB):
//   xT  : 16*4096*512  bf16  =  67,108,864 B   @ 0
//   Wb  : 1152*512     bf16  =   1,179,648 B   @ 67,108,864
//   bp  : 1152         f32   =       4,608 B   @ 68,288,512
//   D'  : 256*4224     bf16  =   2,162,688 B   @ 68,293,120
//   S   : 16*4096*528  u32   = 138,412,032 B   @ 70,455,808
extern "C" void kernel_launch(void* const* d_in, const int* in_sizes, int n_in,
                              void* d_out, int out_size, void* d_ws, size_t ws_size,
                              hipStream_t stream) {
    const float* x    = (const float*)d_in[0];
    const float* W    = (const float*)d_in[1];
    const float* bvec = (const float*)d_in[2];
    float* y = (float*)d_out;
    char* ws = (char*)d_ws;

    unsigned short* xT = (unsigned short*)(ws);
    unsigned short* Wb = (unsigned short*)(ws + 67108864);
    float*          bp = (float*)(ws + 68288512);
    unsigned short* D  = (unsigned short*)(ws + 68293120);
    unsigned*       S  = (unsigned*)(ws + 70455808);

    transpose_x<<<dim3(128, 16, BATCH), dim3(32, 8), 0, stream>>>(x, xT);
    pack_W<<<dim3(1152), dim3(256), 0, stream>>>(W, bvec, Wb, bp);
    build_D<<<dim3((256 * K2 + 255) / 256), dim3(256), 0, stream>>>(D);

    // GEMM1: 3 m-tiles per block for guaranteed B-tile L2 reuse
    gemm1_kernel<<<dim3(32, 3, BATCH), dim3(256), 0, stream>>>(Wb, xT, bp, S);

    // GEMM2: per-wave-pipelined OLA GEMM (1 barrier per kk, DCE-hardened)
    gemm2_kernel<<<dim3(33, 2, BATCH), dim3(256), 0, stream>>>(
        D, (const unsigned short*)S, y);
}